// Round 12
// baseline (326.346 us; speedup 1.0000x reference)
//
#include <hip/hip_runtime.h>

#define Bv   2
#define Dd   160
#define Hh   192
#define Ww   160
#define HW   (Hh*Ww)          // 30720
#define DHW  (Dd*Hh*Ww)       // 4915200
#define NTOT (Bv*DHW)         // 9830400
#define INV729 (1.0f/729.0f)

typedef _Float16 f16;

// ---- vector helpers: storage type TS in {float, f16}, all math in f32 ----
__device__ __forceinline__ float4 LD4(const float* p) {
    return *reinterpret_cast<const float4*>(p);
}
__device__ __forceinline__ float4 LD4(const f16* p) {
    union { uint2 u; f16 h[4]; } c;
    c.u = *reinterpret_cast<const uint2*>(p);
    return make_float4((float)c.h[0], (float)c.h[1], (float)c.h[2], (float)c.h[3]);
}
__device__ __forceinline__ void ST4(float* p, float4 v) {
    *reinterpret_cast<float4*>(p) = v;
}
__device__ __forceinline__ void ST4(f16* p, float4 v) {
    union { uint2 u; f16 h[4]; } c;
    c.h[0] = (f16)v.x; c.h[1] = (f16)v.y; c.h[2] = (f16)v.z; c.h[3] = (f16)v.w;
    *reinterpret_cast<uint2*>(p) = c.u;
}
__device__ __forceinline__ float4 add4(float4 a, float4 b) {
    return make_float4(a.x+b.x, a.y+b.y, a.z+b.z, a.w+b.w);
}
__device__ __forceinline__ float4 zero4() { return make_float4(0.f,0.f,0.f,0.f); }

// ---- xsum5: 5-channel 9-wide x-box-sums at 4 x-positions (pure, no accum) ----
__device__ __forceinline__ void xsum5(const float* __restrict__ rI,
                                      const float* __restrict__ rJ,
                                      int x0, float4 s[5]) {
    float wI[12], wJ[12];
    if (x0 >= 4 && x0 <= Ww - 8) {                     // fast interior path
        float4 a0 = LD4(rI + x0 - 4), a1 = LD4(rI + x0), a2 = LD4(rI + x0 + 4);
        wI[0]=a0.x; wI[1]=a0.y; wI[2]=a0.z;  wI[3]=a0.w;
        wI[4]=a1.x; wI[5]=a1.y; wI[6]=a1.z;  wI[7]=a1.w;
        wI[8]=a2.x; wI[9]=a2.y; wI[10]=a2.z; wI[11]=a2.w;
        float4 b0 = LD4(rJ + x0 - 4), b1 = LD4(rJ + x0), b2 = LD4(rJ + x0 + 4);
        wJ[0]=b0.x; wJ[1]=b0.y; wJ[2]=b0.z;  wJ[3]=b0.w;
        wJ[4]=b1.x; wJ[5]=b1.y; wJ[6]=b1.z;  wJ[7]=b1.w;
        wJ[8]=b2.x; wJ[9]=b2.y; wJ[10]=b2.z; wJ[11]=b2.w;
    } else {
        #pragma unroll
        for (int i = 0; i < 12; ++i) {
            int xx = x0 - 4 + i;
            bool ok = (xx >= 0) && (xx < Ww);
            wI[i] = ok ? rI[xx] : 0.f;
            wJ[i] = ok ? rJ[xx] : 0.f;
        }
    }
#define CH(cidx, EXPR) {                                                    \
        float t[12];                                                        \
        _Pragma("unroll")                                                   \
        for (int i = 0; i < 12; ++i) {                                      \
            float a = wI[i], b = wJ[i]; (void)a; (void)b;                   \
            t[i] = (EXPR);                                                  \
        }                                                                   \
        float s0 = ((t[0]+t[1])+(t[2]+t[3]))+((t[4]+t[5])+(t[6]+t[7]))+t[8];\
        float s1 = s0 - t[0] + t[9];                                        \
        float s2 = s1 - t[1] + t[10];                                       \
        float s3 = s2 - t[2] + t[11];                                       \
        s[cidx] = make_float4(s0, s1, s2, s3);                              \
    }
    CH(0, a); CH(1, b); CH(2, a * a); CH(3, b * b); CH(4, a * b);
#undef CH
}

// ---- cc4: finalize 4 voxels from 5-channel window sums, return their cc sum ----
__device__ __forceinline__ float cc4(const float4 S[5]) {
    float acc = 0.f;
#define FIN(CMP) {                                                      \
        float SI = S[0].CMP, SJ = S[1].CMP, SII = S[2].CMP,             \
              SJJ = S[3].CMP, SIJ = S[4].CMP;                           \
        float uI = SI * INV729, uJ = SJ * INV729;                       \
        float cross = SIJ - uJ * SI - uI * SJ + uI * uJ * 729.0f;       \
        float Iv = SII - 2.0f * uI * SI + uI * uI * 729.0f;             \
        float Jv = SJJ - 2.0f * uJ * SJ + uJ * uJ * 729.0f;             \
        acc += cross * cross / (Iv * Jv + 1e-5f);                       \
    }
    FIN(x) FIN(y) FIN(z) FIN(w)
#undef FIN
    return acc;
}

__device__ __forceinline__ void block_reduce_atomic(float acc, float* out) {
    for (int off = 32; off > 0; off >>= 1) acc += __shfl_down(acc, off);
    __shared__ float red[4];
    int lane = threadIdx.x & 63, wid = threadIdx.x >> 6;
    if (lane == 0) red[wid] = acc;
    __syncthreads();
    if (threadIdx.x == 0)
        atomicAdd(out, (red[0]+red[1]+red[2]+red[3]) * (1.0f/(float)NTOT));
}

// ---------------- k12 v2: x+y pass, independent-batch structure ----------------
// thread -> (b, z, 4 consecutive y, 4 consecutive x). Loads its 12-row window
// as INDEPENDENT row batches (72 vec4 loads, no serial chain), accumulates
// into 4 y-windows with fully unrolled compile-time adds. 2400 blocks.
template<typename TS>
__global__ __launch_bounds__(256)
void k12v2(const float* __restrict__ I, const float* __restrict__ J,
           TS* __restrict__ B) {
    int tid = blockIdx.x * 256 + threadIdx.x;          // 0 .. 614399
    int x4 = tid % (Ww/4);  int t1 = tid / (Ww/4);
    int yg = t1 % (Hh/4);   t1 /= (Hh/4);
    int z  = t1 % Dd;       int b = t1 / Dd;
    int x0 = x4 * 4, y0 = yg * 4;

    const float* sI = I + (size_t)b * DHW + (size_t)z * HW;
    const float* sJ = J + (size_t)b * DHW + (size_t)z * HW;
    TS* dst = B + (size_t)b * DHW + (size_t)z * HW + x0;

    float4 W[4][5];
    #pragma unroll
    for (int k = 0; k < 4; ++k)
        #pragma unroll
        for (int c = 0; c < 5; ++c) W[k][c] = zero4();

#define ROW(rr) {                                                       \
        float4 s[5];                                                    \
        xsum5(sI + (size_t)(y0 - 4 + (rr)) * Ww,                        \
              sJ + (size_t)(y0 - 4 + (rr)) * Ww, x0, s);                \
        _Pragma("unroll")                                               \
        for (int k = 0; k < 4; ++k)                                     \
            if ((rr) - 8 <= k && k <= (rr)) {                           \
                _Pragma("unroll")                                       \
                for (int c = 0; c < 5; ++c)                             \
                    W[k][c] = add4(W[k][c], s[c]);                      \
            }                                                           \
    }

    if (y0 >= 4 && y0 + 7 < Hh) {                      // fast interior: no branches
        #pragma unroll
        for (int rr = 0; rr < 12; ++rr) ROW(rr);
    } else {
        #pragma unroll
        for (int rr = 0; rr < 12; ++rr) {
            int y = y0 - 4 + rr;
            if (y >= 0 && y < Hh) ROW(rr);
        }
    }
#undef ROW

    #pragma unroll
    for (int k = 0; k < 4; ++k) {
        #pragma unroll
        for (int c = 0; c < 5; ++c)
            ST4(dst + (size_t)c * NTOT + (size_t)(y0 + k) * Ww, W[k][c]);
    }
}

// ---------------- k3 v2: z-pass + finalize, independent-batch structure -------
// thread -> (b, 4 consecutive z, y, 4 consecutive x). Loads 12 z-slices x 5 ch
// as 60 INDEPENDENT 8B loads, accumulates into 4 z-windows, finalizes 16 voxels.
template<typename TS>
__global__ __launch_bounds__(256)
void k3v2(const TS* __restrict__ Bb, float* __restrict__ out) {
    int tid = blockIdx.x * 256 + threadIdx.x;          // 0 .. 614399
    int x4 = tid % (Ww/4);  int t1 = tid / (Ww/4);
    int y  = t1 % Hh;       t1 /= Hh;
    int zg = t1 % (Dd/4);   int b = t1 / (Dd/4);
    int z0 = zg * 4;

    const TS* P0 = Bb + (size_t)b * DHW + (size_t)y * Ww + x4 * 4;

    float4 W[4][5];
    #pragma unroll
    for (int k = 0; k < 4; ++k)
        #pragma unroll
        for (int c = 0; c < 5; ++c) W[k][c] = zero4();

#define SLICE(ss) {                                                     \
        const TS* pp = P0 + (size_t)(z0 - 4 + (ss)) * HW;               \
        float4 v[5];                                                    \
        _Pragma("unroll")                                               \
        for (int c = 0; c < 5; ++c) v[c] = LD4(pp + (size_t)c * NTOT);  \
        _Pragma("unroll")                                               \
        for (int k = 0; k < 4; ++k)                                     \
            if ((ss) - 8 <= k && k <= (ss)) {                           \
                _Pragma("unroll")                                       \
                for (int c = 0; c < 5; ++c)                             \
                    W[k][c] = add4(W[k][c], v[c]);                      \
            }                                                           \
    }

    if (z0 >= 4 && z0 + 7 < Dd) {                      // fast interior: no branches
        #pragma unroll
        for (int ss = 0; ss < 12; ++ss) SLICE(ss);
    } else {
        #pragma unroll
        for (int ss = 0; ss < 12; ++ss) {
            int z = z0 - 4 + ss;
            if (z >= 0 && z < Dd) SLICE(ss);
        }
    }
#undef SLICE

    float acc = cc4(W[0]) + cc4(W[1]) + cc4(W[2]) + cc4(W[3]);
    block_reduce_atomic(acc, out);
}

// ---------------- brute-force fallback: ZERO workspace, slow but correct ----
__global__ __launch_bounds__(256)
void k_brute(const float* __restrict__ I, const float* __restrict__ J,
             float* __restrict__ out) {
    int tid = blockIdx.x * 256 + threadIdx.x;          // 0 .. NTOT/4-1
    int x4 = tid % (Ww/4);  int t1 = tid / (Ww/4);
    int y  = t1 % Hh;       t1 /= Hh;
    int z  = t1 % Dd;       int b = t1 / Dd;
    int x0 = x4 * 4;

    const float* bI = I + (size_t)b * DHW;
    const float* bJ = J + (size_t)b * DHW;

    float4 S[5] = {zero4(), zero4(), zero4(), zero4(), zero4()};
    for (int dz = -4; dz <= 4; ++dz) {
        int zz = z + dz;
        if (zz < 0 || zz >= Dd) continue;
        for (int dy = -4; dy <= 4; ++dy) {
            int yy = y + dy;
            if (yy < 0 || yy >= Hh) continue;
            float4 s[5];
            xsum5(bI + (size_t)zz * HW + (size_t)yy * Ww,
                  bJ + (size_t)zz * HW + (size_t)yy * Ww, x0, s);
            #pragma unroll
            for (int c = 0; c < 5; ++c) S[c] = add4(S[c], s[c]);
        }
    }
    block_reduce_atomic(cc4(S), out);
}

extern "C" void kernel_launch(void* const* d_in, const int* in_sizes, int n_in,
                              void* d_out, int out_size, void* d_ws, size_t ws_size,
                              hipStream_t stream) {
    const float* I = (const float*)d_in[0];
    const float* J = (const float*)d_in[1];
    float* out = (float*)d_out;

    hipMemsetAsync(d_out, 0, sizeof(float), stream);   // graph-capture-safe

    const int gk = 614400/256;                         // 2400 blocks

    if (ws_size >= (size_t)5 * NTOT * sizeof(f16)) {
        // f16 intermediates (98.3 MB), all math f32 (round-10: absmax 0.0).
        f16* B = (f16*)d_ws;
        k12v2<f16><<<gk, 256, 0, stream>>>(I, J, B);
        k3v2<f16><<<gk, 256, 0, stream>>>(B, out);
    } else {
        // workspace-free fallback: slow but correct
        k_brute<<<(NTOT/4)/256, 256, 0, stream>>>(I, J, out);
    }
}

// Round 13
// 238.981 us; speedup vs baseline: 1.3656x; 1.3656x over previous
//
#include <hip/hip_runtime.h>

#define Bv   2
#define Dd   160
#define Hh   192
#define Ww   160
#define HW   (Hh*Ww)          // 30720
#define DHW  (Dd*Hh*Ww)       // 4915200
#define NTOT (Bv*DHW)         // 9830400
#define INV729 (1.0f/729.0f)

typedef _Float16 f16;

// ---- vector helpers: storage type TS in {float, f16}, all math in f32 ----
__device__ __forceinline__ float4 LD4(const float* p) {
    return *reinterpret_cast<const float4*>(p);
}
__device__ __forceinline__ float4 LD4(const f16* p) {
    union { uint2 u; f16 h[4]; } c;
    c.u = *reinterpret_cast<const uint2*>(p);
    return make_float4((float)c.h[0], (float)c.h[1], (float)c.h[2], (float)c.h[3]);
}
__device__ __forceinline__ void ST4(float* p, float4 v) {
    *reinterpret_cast<float4*>(p) = v;
}
__device__ __forceinline__ void ST4(f16* p, float4 v) {
    union { uint2 u; f16 h[4]; } c;
    c.h[0] = (f16)v.x; c.h[1] = (f16)v.y; c.h[2] = (f16)v.z; c.h[3] = (f16)v.w;
    *reinterpret_cast<uint2*>(p) = c.u;
}
__device__ __forceinline__ float4 add4(float4 a, float4 b) {
    return make_float4(a.x+b.x, a.y+b.y, a.z+b.z, a.w+b.w);
}
__device__ __forceinline__ float4 sub4(float4 a, float4 b) {
    return make_float4(a.x-b.x, a.y-b.y, a.z-b.z, a.w-b.w);
}
__device__ __forceinline__ float4 mul4(float4 a, float4 b) {
    return make_float4(a.x*b.x, a.y*b.y, a.z*b.z, a.w*b.w);
}
__device__ __forceinline__ float4 zero4() { return make_float4(0.f,0.f,0.f,0.f); }

// ---- rowsum5: add sgn * (5-channel 9-wide x-box-sums at 4 x-positions) ----
// float4-tree variant: per channel, w = v0+v1 (4 ops), s0 = hsum(w)+v2.x,
// then 3 sliding increments — ~15% fewer VALU ops than the serial tree.
__device__ __forceinline__ void rowsum5(const float* __restrict__ rI,
                                        const float* __restrict__ rJ,
                                        int x0, float sgn, float4 S[5]) {
    float4 vI[3], vJ[3];
    if (x0 >= 4 && x0 <= Ww - 8) {                     // fast interior path
        vI[0] = LD4(rI + x0 - 4); vI[1] = LD4(rI + x0); vI[2] = LD4(rI + x0 + 4);
        vJ[0] = LD4(rJ + x0 - 4); vJ[1] = LD4(rJ + x0); vJ[2] = LD4(rJ + x0 + 4);
    } else {
        float wI[12], wJ[12];
        #pragma unroll
        for (int i = 0; i < 12; ++i) {
            int xx = x0 - 4 + i;
            bool ok = (xx >= 0) && (xx < Ww);
            wI[i] = ok ? rI[xx] : 0.f;
            wJ[i] = ok ? rJ[xx] : 0.f;
        }
        vI[0] = make_float4(wI[0],wI[1],wI[2],wI[3]);
        vI[1] = make_float4(wI[4],wI[5],wI[6],wI[7]);
        vI[2] = make_float4(wI[8],wI[9],wI[10],wI[11]);
        vJ[0] = make_float4(wJ[0],wJ[1],wJ[2],wJ[3]);
        vJ[1] = make_float4(wJ[4],wJ[5],wJ[6],wJ[7]);
        vJ[2] = make_float4(wJ[8],wJ[9],wJ[10],wJ[11]);
    }
#define CH(cidx, E0, E1, E2) {                                              \
        float4 t0 = (E0), t1 = (E1), t2 = (E2);                             \
        float4 w = add4(t0, t1);                                            \
        float s0 = ((w.x + w.y) + (w.z + w.w)) + t2.x;                      \
        float s1 = s0 - t0.x + t2.y;                                        \
        float s2 = s1 - t0.y + t2.z;                                        \
        float s3 = s2 - t0.z + t2.w;                                        \
        S[cidx].x += sgn * s0; S[cidx].y += sgn * s1;                       \
        S[cidx].z += sgn * s2; S[cidx].w += sgn * s3;                       \
    }
    CH(0, vI[0], vI[1], vI[2]);
    CH(1, vJ[0], vJ[1], vJ[2]);
    CH(2, mul4(vI[0],vI[0]), mul4(vI[1],vI[1]), mul4(vI[2],vI[2]));
    CH(3, mul4(vJ[0],vJ[0]), mul4(vJ[1],vJ[1]), mul4(vJ[2],vJ[2]));
    CH(4, mul4(vI[0],vJ[0]), mul4(vI[1],vJ[1]), mul4(vI[2],vJ[2]));
#undef CH
}

// ---- cc4: finalize 4 voxels from 5-channel window sums, return their cc sum ----
__device__ __forceinline__ float cc4(const float4 S[5]) {
    float acc = 0.f;
#define FIN(CMP) {                                                      \
        float SI = S[0].CMP, SJ = S[1].CMP, SII = S[2].CMP,             \
              SJJ = S[3].CMP, SIJ = S[4].CMP;                           \
        float uI = SI * INV729, uJ = SJ * INV729;                       \
        float cross = SIJ - uJ * SI - uI * SJ + uI * uJ * 729.0f;       \
        float Iv = SII - 2.0f * uI * SI + uI * uI * 729.0f;             \
        float Jv = SJJ - 2.0f * uJ * SJ + uJ * uJ * 729.0f;             \
        acc += cross * cross / (Iv * Jv + 1e-5f);                       \
    }
    FIN(x) FIN(y) FIN(z) FIN(w)
#undef FIN
    return acc;
}

__device__ __forceinline__ void block_reduce_atomic(float acc, float* out) {
    for (int off = 32; off > 0; off >>= 1) acc += __shfl_down(acc, off);
    __shared__ float red[4];
    int lane = threadIdx.x & 63, wid = threadIdx.x >> 6;
    if (lane == 0) red[wid] = acc;
    __syncthreads();
    if (threadIdx.x == 0)
        atomicAdd(out, (red[0]+red[1]+red[2]+red[3]) * (1.0f/(float)NTOT));
}

// ---------------- k12: fused x+y pass, y-running-window ----------------
// Round-5-proven geometry: y-chunk 16 -> 2.5 rowsums/output, 600 blocks,
// ~56 VGPR. f16 stores (halves k3's read bytes; k3 is load-byte-bound).
template<typename TS>
__global__ __launch_bounds__(256)
void k12_xy(const float* __restrict__ I, const float* __restrict__ J,
            TS* __restrict__ B) {
    int tid = blockIdx.x * 256 + threadIdx.x;          // 0 .. 153599
    int x4 = tid % (Ww/4);  int t1 = tid / (Ww/4);
    int yc = t1 % (Hh/16);  t1 /= (Hh/16);
    int z  = t1 % Dd;       int b = t1 / Dd;
    int x0 = x4 * 4, y0 = yc * 16;

    const float* sI = I + (size_t)b * DHW + (size_t)z * HW;
    const float* sJ = J + (size_t)b * DHW + (size_t)z * HW;
    TS* dst = B + (size_t)b * DHW + (size_t)z * HW + x0;

    float4 S[5] = {zero4(), zero4(), zero4(), zero4(), zero4()};
    #pragma unroll
    for (int dy = -4; dy <= 3; ++dy) {                 // preload y0-4 .. y0+3
        int y = y0 + dy;
        if (y >= 0) rowsum5(sI + (size_t)y * Ww, sJ + (size_t)y * Ww, x0, 1.f, S);
    }
    #pragma unroll 4
    for (int y = y0; y < y0 + 16; ++y) {
        int yt = y + 4;
        if (yt < Hh) rowsum5(sI + (size_t)yt * Ww, sJ + (size_t)yt * Ww, x0, 1.f, S);
        ST4(dst + (size_t)y * Ww,                    S[0]);
        ST4(dst + (size_t)NTOT     + (size_t)y * Ww, S[1]);
        ST4(dst + (size_t)2 * NTOT + (size_t)y * Ww, S[2]);
        ST4(dst + (size_t)3 * NTOT + (size_t)y * Ww, S[3]);
        ST4(dst + (size_t)4 * NTOT + (size_t)y * Ww, S[4]);
        int yo = y - 4;
        if (yo >= 0) rowsum5(sI + (size_t)yo * Ww, sJ + (size_t)yo * Ww, x0, -1.f, S);
    }
}

// ---------------- k3: z-pass + finalize (round-10 proven config) ----------
// thread -> (b, z-chunk of 8, y, 4 consecutive x); 1200 blocks, f16 reads.
template<typename TS>
__global__ __launch_bounds__(256)
void k3_zpass(const TS* __restrict__ Bb, float* __restrict__ out) {
    int tid = blockIdx.x * 256 + threadIdx.x;          // 0 .. 307199
    int x4 = tid % (Ww/4);  int t1 = tid / (Ww/4);
    int y  = t1 % Hh;       t1 /= Hh;
    int zc = t1 % (Dd/8);   int b = t1 / (Dd/8);
    int z0 = zc * 8;

    size_t base = (size_t)b * DHW + (size_t)y * Ww + x4 * 4;
    const TS* P0 = Bb + base;

    float4 S[5] = {zero4(), zero4(), zero4(), zero4(), zero4()};

#define LOADADD(zi) {                                                   \
        const TS* pp = P0 + (size_t)(zi) * HW;                          \
        S[0] = add4(S[0], LD4(pp));                                     \
        S[1] = add4(S[1], LD4(pp + (size_t)NTOT));                      \
        S[2] = add4(S[2], LD4(pp + (size_t)2 * NTOT));                  \
        S[3] = add4(S[3], LD4(pp + (size_t)3 * NTOT));                  \
        S[4] = add4(S[4], LD4(pp + (size_t)4 * NTOT));                  \
    }
#define LOADSUB(zi) {                                                   \
        const TS* pp = P0 + (size_t)(zi) * HW;                          \
        S[0] = sub4(S[0], LD4(pp));                                     \
        S[1] = sub4(S[1], LD4(pp + (size_t)NTOT));                      \
        S[2] = sub4(S[2], LD4(pp + (size_t)2 * NTOT));                  \
        S[3] = sub4(S[3], LD4(pp + (size_t)3 * NTOT));                  \
        S[4] = sub4(S[4], LD4(pp + (size_t)4 * NTOT));                  \
    }

    #pragma unroll
    for (int dz = -4; dz <= 3; ++dz) {                 // preload z0-4 .. z0+3
        int z = z0 + dz;
        if (z >= 0) LOADADD(z);
    }

    float acc = 0.f;
    #pragma unroll
    for (int z = z0; z < z0 + 8; ++z) {
        int zt = z + 4;
        if (zt < Dd) LOADADD(zt);
        acc += cc4(S);
        int zo = z - 4;
        if (zo >= 0) LOADSUB(zo);
    }
#undef LOADADD
#undef LOADSUB

    block_reduce_atomic(acc, out);
}

// ---------------- brute-force fallback: ZERO workspace, slow but correct ----
__global__ __launch_bounds__(256)
void k_brute(const float* __restrict__ I, const float* __restrict__ J,
             float* __restrict__ out) {
    int tid = blockIdx.x * 256 + threadIdx.x;          // 0 .. NTOT/4-1
    int x4 = tid % (Ww/4);  int t1 = tid / (Ww/4);
    int y  = t1 % Hh;       t1 /= Hh;
    int z  = t1 % Dd;       int b = t1 / Dd;
    int x0 = x4 * 4;

    const float* bI = I + (size_t)b * DHW;
    const float* bJ = J + (size_t)b * DHW;

    float4 S[5] = {zero4(), zero4(), zero4(), zero4(), zero4()};
    for (int dz = -4; dz <= 4; ++dz) {
        int zz = z + dz;
        if (zz < 0 || zz >= Dd) continue;
        for (int dy = -4; dy <= 4; ++dy) {
            int yy = y + dy;
            if (yy < 0 || yy >= Hh) continue;
            rowsum5(bI + (size_t)zz * HW + (size_t)yy * Ww,
                    bJ + (size_t)zz * HW + (size_t)yy * Ww, x0, 1.f, S);
        }
    }
    block_reduce_atomic(cc4(S), out);
}

extern "C" void kernel_launch(void* const* d_in, const int* in_sizes, int n_in,
                              void* d_out, int out_size, void* d_ws, size_t ws_size,
                              hipStream_t stream) {
    const float* I = (const float*)d_in[0];
    const float* J = (const float*)d_in[1];
    float* out = (float*)d_out;

    hipMemsetAsync(d_out, 0, sizeof(float), stream);   // graph-capture-safe

    const int g12 = 153600/256;                        // 600 blocks
    const int g3  = 307200/256;                        // 1200 blocks

    if (ws_size >= (size_t)5 * NTOT * sizeof(f16)) {
        // f16 intermediates (98.3 MB), all math f32 (round-10: absmax 0.0).
        f16* B = (f16*)d_ws;
        k12_xy<f16><<<g12, 256, 0, stream>>>(I, J, B);
        k3_zpass<f16><<<g3, 256, 0, stream>>>(B, out);
    } else {
        // workspace-free fallback: slow but correct
        k_brute<<<(NTOT/4)/256, 256, 0, stream>>>(I, J, out);
    }
}